// Round 7
// baseline (322.418 us; speedup 1.0000x reference)
//
#include <hip/hip_runtime.h>
#include <hip/hip_bf16.h>
#include <math.h>

#define BB 32
#define SS 4096
#define HH 256

typedef __bf16 bf16x8 __attribute__((ext_vector_type(8)));
typedef float f32x4 __attribute__((ext_vector_type(4)));

__device__ inline bf16x8 cvt8(const float4& x, const float4& y) {
    union { __hip_bfloat162 p[4]; bf16x8 v; } u;
    u.p[0] = __float22bfloat162_rn(make_float2(x.x, x.y));
    u.p[1] = __float22bfloat162_rn(make_float2(x.z, x.w));
    u.p[2] = __float22bfloat162_rn(make_float2(y.x, y.y));
    u.p[3] = __float22bfloat162_rn(make_float2(y.z, y.w));
    return u.v;
}

// tanh via exp path: ~6 VALU ops. |rel err| ~1e-7.
__device__ inline float fast_tanh(float x) {
    float xc = fminf(fmaxf(x, -10.f), 10.f);
    float e  = __expf(2.f * xc);
    return (e - 1.f) * __builtin_amdgcn_rcpf(e + 1.f);
}

// ---------------------------------------------------------------------------
// Prep (fused): blocks 0..255 swizzle W2 -> bf16 MFMA-B order;
// blocks 256..287: qq[b][h] = hidden[b]@W1[:,h] + W1_b[h] + W2_b[h];
// block 288: M = sum_h |V_w[h]| (fixed softmax shift; V_b cancels).
// ---------------------------------------------------------------------------
__global__ void prep_kernel(const float* __restrict__ W2_w,
                            ushort* __restrict__ w2sw,
                            const float* __restrict__ hidden,
                            const float* __restrict__ W1_w,
                            const float* __restrict__ W1_b,
                            const float* __restrict__ W2_b,
                            const float* __restrict__ V_w,
                            float* __restrict__ qq,
                            float* __restrict__ Mout) {
    __shared__ float red[HH];
    const int t = threadIdx.x;
    if (blockIdx.x < 256) {
        const int i = blockIdx.x * 256 + t;
        const int j    = i & 7;
        const int lane = (i >> 3) & 63;
        const int nt   = (i >> 9) & 15;
        const int kc   = i >> 13;
        const int k = kc * 32 + ((lane >> 4) & 3) * 8 + j;
        const int n = nt * 16 + (lane & 15);
        __hip_bfloat16 h = __float2bfloat16(W2_w[k * HH + n]);
        w2sw[i] = *(ushort*)&h;
    } else if (blockIdx.x < 256 + BB) {
        const int b = blockIdx.x - 256;
        red[t] = hidden[b * HH + t];
        __syncthreads();
        float acc = 0.f;
#pragma unroll 16
        for (int k = 0; k < HH; ++k)
            acc = fmaf(red[k], W1_w[k * HH + t], acc);
        qq[b * HH + t] = acc + W1_b[t] + W2_b[t];
    } else {
        red[t] = fabsf(V_w[t]);
        __syncthreads();
        for (int off = 128; off > 0; off >>= 1) {
            if (t < off) red[t] += red[t + off];
            __syncthreads();
        }
        if (t == 0) Mout[0] = red[0];
    }
}

// ---------------------------------------------------------------------------
// Fused score + partial-context. grid 512 x block 256 (4 waves, 2m x 2n).
// Each block runs 4 sequential 64-row tiles (same b, consecutive c).
// Forced software pipeline: A (enc, HBM) prefetch distance 2 (ring-4),
// B (W2 L2-resident) distance 1 (ring-2); asm memory fence pins the loads
// before the MFMA group (R6's compiler sank them: VGPR=64 = no pipeline).
// Ring phases are tile-invariant (8 mod 4 == 0), and kc=6,7 prefetch the
// NEXT tile's first iterations so the load latency hides under the tanh
// epilogue. No __syncthreads in the K-loop.
// ---------------------------------------------------------------------------
__global__ __launch_bounds__(256, 2)
void score_ctx_kernel(const float* __restrict__ enc,
                      const ushort* __restrict__ w2sw,
                      const float* __restrict__ qq,
                      const float* __restrict__ V_w,
                      const float* __restrict__ Mptr,
                      float* __restrict__ wtilde_out,
                      float* __restrict__ part) {
    __shared__ float sc_lds[64];
    __shared__ float accl[4][HH];

    const int t    = threadIdx.x;
    const int wave = t >> 6;
    const int lane = t & 63;
    const int mw   = wave & 1;
    const int nw   = wave >> 1;
    const int l15  = lane & 15;
    const int quad = lane >> 4;

    const int tile0 = blockIdx.x * 4;           // 2048 tiles = 512 blk x 4
    const int b     = tile0 >> 6;               // same b for all 4 tiles

    const bf16x8* bgl = (const bf16x8*)w2sw + (size_t)(nw * 8) * 64 + lane;

    // per-wave loop-invariant epilogue data
    const float Mv = Mptr[0];
    float qv[8], vv[8];
#pragma unroll
    for (int nt = 0; nt < 8; ++nt) {
        const int n = nw * 128 + nt * 16 + l15;
        qv[nt] = qq[b * HH + n];
        vv[nt] = V_w[n];
    }

    // A base for tile: rows c*64 + mw*32 + {0,16} + l15, k = kc*32 + quad*8
    auto abase = [&](int tile) -> const float* {
        const int c = tile & 63;
        return enc + ((size_t)(b * SS + c * 64 + mw * 32 + l15)) * HH + quad * 8;
    };

    bf16x8 bq[2][8];          // B ring-2
    float4 ax[4][2], ay[4][2]; // A ring-4, [slot][mt]

    const float* aptr = abase(tile0);
    // preload: B iter0 -> slot0, A iters 0,1 -> slots 0,1
#pragma unroll
    for (int nt = 0; nt < 8; ++nt) bq[0][nt] = bgl[nt * 64];
#pragma unroll
    for (int s = 0; s < 2; ++s)
#pragma unroll
        for (int mt = 0; mt < 2; ++mt) {
            const float* p = aptr + (size_t)mt * 16 * HH + s * 32;
            ax[s][mt] = *(const float4*)p;
            ay[s][mt] = *(const float4*)(p + 4);
        }

    for (int tt = 0; tt < 4; ++tt) {
        const int tile = tile0 + tt;
        const int c    = tile & 63;
        const int s0   = c * 64;
        const float* aptrN = abase(tt < 3 ? tile + 1 : tile0);  // wrap: harmless

        f32x4 acc[2][8];
#pragma unroll
        for (int mt = 0; mt < 2; ++mt)
#pragma unroll
            for (int nt = 0; nt < 8; ++nt) acc[mt][nt] = (f32x4)0.f;

#pragma unroll
        for (int kc = 0; kc < 8; ++kc) {
            // B prefetch: virtual iter kc+1 (W2 is tile-invariant -> mod 8)
            {
                const int p = (kc + 1) & 7;
#pragma unroll
                for (int nt = 0; nt < 8; ++nt)
                    bq[(kc + 1) & 1][nt] = bgl[p * 1024 + nt * 64];
            }
            // A prefetch: virtual iter kc+2 (kc>=6 -> next tile's iters 0,1)
            {
                const int slot = (kc + 2) & 3;
                const float* pb = (kc < 6) ? (aptr + (kc + 2) * 32)
                                           : (aptrN + (kc - 6) * 32);
#pragma unroll
                for (int mt = 0; mt < 2; ++mt) {
                    const float* p = pb + (size_t)mt * 16 * HH;
                    ax[slot][mt] = *(const float4*)p;
                    ay[slot][mt] = *(const float4*)(p + 4);
                }
            }
            // pin the prefetch loads above the MFMA group
            asm volatile("" ::: "memory");

            const int cs = kc & 3, cb = kc & 1;
            bf16x8 af0 = cvt8(ax[cs][0], ay[cs][0]);
            bf16x8 af1 = cvt8(ax[cs][1], ay[cs][1]);
#pragma unroll
            for (int nt = 0; nt < 8; ++nt) {
                acc[0][nt] = __builtin_amdgcn_mfma_f32_16x16x32_bf16(
                    af0, bq[cb][nt], acc[0][nt], 0, 0, 0);
                acc[1][nt] = __builtin_amdgcn_mfma_f32_16x16x32_bf16(
                    af1, bq[cb][nt], acc[1][nt], 0, 0, 0);
            }
        }
        aptr = aptrN;

        // Epilogue: C layout col = l15, local row = quad*4 + r.
        float p[2][4] = {{0.f, 0.f, 0.f, 0.f}, {0.f, 0.f, 0.f, 0.f}};
#pragma unroll
        for (int nt = 0; nt < 8; ++nt) {
#pragma unroll
            for (int mt = 0; mt < 2; ++mt)
#pragma unroll
                for (int r = 0; r < 4; ++r)
                    p[mt][r] = fmaf(vv[nt], fast_tanh(qv[nt] + acc[mt][nt][r]),
                                    p[mt][r]);
        }
#pragma unroll
        for (int off = 1; off < 16; off <<= 1)
#pragma unroll
            for (int mt = 0; mt < 2; ++mt)
#pragma unroll
                for (int r = 0; r < 4; ++r)
                    p[mt][r] += __shfl_xor(p[mt][r], off);

        if (nw == 0 && l15 == 0) {
#pragma unroll
            for (int mt = 0; mt < 2; ++mt)
                *(float4*)&sc_lds[mw * 32 + mt * 16 + quad * 4] =
                    make_float4(p[mt][0], p[mt][1], p[mt][2], p[mt][3]);
        }
        __syncthreads();
        if (nw == 1 && l15 == 0) {
#pragma unroll
            for (int mt = 0; mt < 2; ++mt) {
                const int row = mw * 32 + mt * 16 + quad * 4;
                float4 h = *(const float4*)&sc_lds[row];
                float4 v = make_float4(__expf(h.x + p[mt][0] - Mv),
                                       __expf(h.y + p[mt][1] - Mv),
                                       __expf(h.z + p[mt][2] - Mv),
                                       __expf(h.w + p[mt][3] - Mv));
                *(float4*)&sc_lds[row] = v;
                *(float4*)&wtilde_out[b * SS + s0 + row] = v;
            }
        }
        __syncthreads();

        // Local ctx partial over this tile's 64 rows (L2-hot: just streamed).
        const int tr = t >> 6;
        const int h0 = (t & 63) * 4;
        float4 a = make_float4(0.f, 0.f, 0.f, 0.f);
        const float* ep = enc + ((size_t)(b * SS + s0)) * HH;
#pragma unroll
        for (int jj = 0; jj < 16; ++jj) {
            const int j = jj * 4 + tr;
            const float4 e = *(const float4*)(ep + (size_t)j * HH + h0);
            const float w = sc_lds[j];
            a.x = fmaf(w, e.x, a.x);
            a.y = fmaf(w, e.y, a.y);
            a.z = fmaf(w, e.z, a.z);
            a.w = fmaf(w, e.w, a.w);
        }
        *(float4*)&accl[tr][h0] = a;
        __syncthreads();

        part[((size_t)(b * 64 + c)) * HH + t] =
            accl[0][t] + accl[1][t] + accl[2][t] + accl[3][t];
        // next tile's K-loop is ~5k cycles away; sc_lds rewrite is also
        // guarded by the barrier above plus the nw==0 write's own barrier.
    }
}

// ---------------------------------------------------------------------------
// Finish: grid (BB), block 256. l = sum_s wtilde (read from d_out),
// weights normalized in place; ctx = (sum_c part)/l.
// ---------------------------------------------------------------------------
__global__ __launch_bounds__(256)
void finish_kernel(const float* __restrict__ part,
                   float* __restrict__ weights_out,
                   float* __restrict__ ctx_out) {
    __shared__ float red[256];
    __shared__ float linv_s;
    const int b = blockIdx.x;
    const int t = threadIdx.x;

    float4* wo4 = (float4*)(weights_out + (size_t)b * SS);
    float4 vals[4];
    float l = 0.f;
#pragma unroll
    for (int i = 0; i < 4; ++i) {
        vals[i] = wo4[i * 256 + t];
        l += vals[i].x + vals[i].y + vals[i].z + vals[i].w;
    }
    red[t] = l;
    __syncthreads();
    for (int off = 128; off > 0; off >>= 1) {
        if (t < off) red[t] += red[t + off];
        __syncthreads();
    }
    if (t == 0) linv_s = 1.f / red[0];
    __syncthreads();
    const float linv = linv_s;

#pragma unroll
    for (int i = 0; i < 4; ++i) {
        const float4 v = vals[i];
        wo4[i * 256 + t] =
            make_float4(v.x * linv, v.y * linv, v.z * linv, v.w * linv);
    }

    float a = 0.f;
#pragma unroll 8
    for (int c = 0; c < 64; ++c)
        a += part[((size_t)(b * 64 + c)) * HH + t];
    ctx_out[b * HH + t] = a * linv;
}

// ---------------------------------------------------------------------------
extern "C" void kernel_launch(void* const* d_in, const int* in_sizes, int n_in,
                              void* d_out, int out_size, void* d_ws, size_t ws_size,
                              hipStream_t stream) {
    const float* hidden = (const float*)d_in[0];
    const float* enc    = (const float*)d_in[1];
    const float* W1_w   = (const float*)d_in[2];
    const float* W1_b   = (const float*)d_in[3];
    const float* W2_w   = (const float*)d_in[4];
    const float* W2_b   = (const float*)d_in[5];
    const float* V_w    = (const float*)d_in[6];
    const float* V_b    = (const float*)d_in[7];
    (void)V_b;  // cancels in the shifted softmax

    float* out_weights = (float*)d_out;                 // B*S
    float* out_ctx     = (float*)d_out + BB * SS;       // B*H

    float* ws      = (float*)d_ws;
    float* ws_qq   = ws;                                 // 8192
    float* ws_part = ws_qq + BB * HH;                    // 524288
    float* ws_M    = ws_part + BB * 64 * HH;             // 1
    ushort* ws_w2  = (ushort*)(ws_M + 4);                // 65536 bf16

    prep_kernel<<<dim3(256 + BB + 1), dim3(256), 0, stream>>>(
        W2_w, ws_w2, hidden, W1_w, W1_b, W2_b, V_w, ws_qq, ws_M);
    score_ctx_kernel<<<dim3(512), dim3(256), 0, stream>>>(
        enc, ws_w2, ws_qq, V_w, ws_M, out_weights, ws_part);
    finish_kernel<<<dim3(BB), dim3(256), 0, stream>>>(
        ws_part, out_weights, out_ctx);
}

// Round 8
// 258.162 us; speedup vs baseline: 1.2489x; 1.2489x over previous
//
#include <hip/hip_runtime.h>
#include <hip/hip_bf16.h>
#include <math.h>

#define BB 32
#define SS 4096
#define HH 256

typedef __bf16 bf16x8 __attribute__((ext_vector_type(8)));
typedef float f32x4 __attribute__((ext_vector_type(4)));

__device__ inline bf16x8 cvt8(const float4& x, const float4& y) {
    union { __hip_bfloat162 p[4]; bf16x8 v; } u;
    u.p[0] = __float22bfloat162_rn(make_float2(x.x, x.y));
    u.p[1] = __float22bfloat162_rn(make_float2(x.z, x.w));
    u.p[2] = __float22bfloat162_rn(make_float2(y.x, y.y));
    u.p[3] = __float22bfloat162_rn(make_float2(y.z, y.w));
    return u.v;
}

// tanh via exp path: ~6 VALU ops. |rel err| ~1e-7.
__device__ inline float fast_tanh(float x) {
    float xc = fminf(fmaxf(x, -10.f), 10.f);
    float e  = __expf(2.f * xc);
    return (e - 1.f) * __builtin_amdgcn_rcpf(e + 1.f);
}

// ---------------------------------------------------------------------------
// Prep (fused): blocks 0..255 swizzle W2 -> bf16 MFMA-B order;
// blocks 256..287: qq[b][h] = hidden[b]@W1[:,h] + W1_b[h] + W2_b[h];
// block 288: M = sum_h |V_w[h]| (fixed softmax shift; V_b cancels).
// ---------------------------------------------------------------------------
__global__ void prep_kernel(const float* __restrict__ W2_w,
                            ushort* __restrict__ w2sw,
                            const float* __restrict__ hidden,
                            const float* __restrict__ W1_w,
                            const float* __restrict__ W1_b,
                            const float* __restrict__ W2_b,
                            const float* __restrict__ V_w,
                            float* __restrict__ qq,
                            float* __restrict__ Mout) {
    __shared__ float red[HH];
    const int t = threadIdx.x;
    if (blockIdx.x < 256) {
        const int i = blockIdx.x * 256 + t;
        const int j    = i & 7;
        const int lane = (i >> 3) & 63;
        const int nt   = (i >> 9) & 15;
        const int kc   = i >> 13;
        const int k = kc * 32 + ((lane >> 4) & 3) * 8 + j;
        const int n = nt * 16 + (lane & 15);
        __hip_bfloat16 h = __float2bfloat16(W2_w[k * HH + n]);
        w2sw[i] = *(ushort*)&h;
    } else if (blockIdx.x < 256 + BB) {
        const int b = blockIdx.x - 256;
        red[t] = hidden[b * HH + t];
        __syncthreads();
        float acc = 0.f;
#pragma unroll 16
        for (int k = 0; k < HH; ++k)
            acc = fmaf(red[k], W1_w[k * HH + t], acc);
        qq[b * HH + t] = acc + W1_b[t] + W2_b[t];
    } else {
        red[t] = fabsf(V_w[t]);
        __syncthreads();
        for (int off = 128; off > 0; off >>= 1) {
            if (t < off) red[t] += red[t + off];
            __syncthreads();
        }
        if (t == 0) Mout[0] = red[0];
    }
}

// ---------------------------------------------------------------------------
// Fused score + partial-context. grid (64, BB), block 256 (4 waves, 2m x 2n),
// tile 64 s-rows x 256 n. One tile per block (R6 TLP) + forced software
// pipeline (R7 mechanism): A (enc, HBM) ring-3 prefetch distance 2,
// B (W2, L2-resident) ring-2 distance 1; asm memory fences pin the loads so
// the compiler cannot sink them to their uses (R5/R6 at VGPR=64 had zero
// loads in flight -> every load ate full latency, ~60k stall cyc/tile-wave).
// No __syncthreads in the K-loop.
// ---------------------------------------------------------------------------
__global__ __launch_bounds__(256, 2)
void score_ctx_kernel(const float* __restrict__ enc,
                      const ushort* __restrict__ w2sw,
                      const float* __restrict__ qq,
                      const float* __restrict__ V_w,
                      const float* __restrict__ Mptr,
                      float* __restrict__ wtilde_out,
                      float* __restrict__ part) {
    __shared__ float sc_lds[64];
    __shared__ float accl[4][HH];

    const int t    = threadIdx.x;
    const int b    = blockIdx.y;
    const int c    = blockIdx.x;
    const int s0   = c * 64;
    const int wave = t >> 6;
    const int lane = t & 63;
    const int mw   = wave & 1;
    const int nw   = wave >> 1;
    const int l15  = lane & 15;
    const int quad = lane >> 4;

    f32x4 acc[2][8];
#pragma unroll
    for (int mt = 0; mt < 2; ++mt)
#pragma unroll
        for (int nt = 0; nt < 8; ++nt) acc[mt][nt] = (f32x4)0.f;

    // B: global bf16x8 index kc*1024 + (nw*8+nt)*64 + lane
    const bf16x8* bgl = (const bf16x8*)w2sw + (size_t)(nw * 8) * 64 + lane;
    // A: rows s0 + mw*32 + mt*16 + l15, k = kc*32 + quad*8 + j
    const float* aptr0 =
        enc + ((size_t)(b * SS + s0 + mw * 32 + l15)) * HH + quad * 8;
    const float* aptr1 = aptr0 + (size_t)16 * HH;

    bf16x8 bq[2][8];           // B ring-2 (64 VGPR)
    float4 ax[3][2], ay[3][2]; // A ring-3 (48 VGPR), [slot][mt]

    // prologue: B iters 0,1; A iters 0,1,2
#pragma unroll
    for (int s = 0; s < 2; ++s)
#pragma unroll
        for (int nt = 0; nt < 8; ++nt) bq[s][nt] = bgl[s * 1024 + nt * 64];
#pragma unroll
    for (int s = 0; s < 3; ++s) {
        ax[s][0] = *(const float4*)(aptr0 + s * 32);
        ay[s][0] = *(const float4*)(aptr0 + s * 32 + 4);
        ax[s][1] = *(const float4*)(aptr1 + s * 32);
        ay[s][1] = *(const float4*)(aptr1 + s * 32 + 4);
    }
    asm volatile("" ::: "memory");

#pragma unroll
    for (int kc = 0; kc < 8; ++kc) {
        const int sa = kc % 3;
        const int sb = kc & 1;
        // consume A[kc] (waitcnt here covers a load issued 3 iters ago)
        bf16x8 af0 = cvt8(ax[sa][0], ay[sa][0]);
        bf16x8 af1 = cvt8(ax[sa][1], ay[sa][1]);
        // refill freed A slot with A[kc+3]
        if (kc + 3 < 8) {
            const int o = (kc + 3) * 32;
            ax[sa][0] = *(const float4*)(aptr0 + o);
            ay[sa][0] = *(const float4*)(aptr0 + o + 4);
            ax[sa][1] = *(const float4*)(aptr1 + o);
            ay[sa][1] = *(const float4*)(aptr1 + o + 4);
        }
        asm volatile("" ::: "memory");
#pragma unroll
        for (int nt = 0; nt < 8; ++nt) {
            acc[0][nt] = __builtin_amdgcn_mfma_f32_16x16x32_bf16(
                af0, bq[sb][nt], acc[0][nt], 0, 0, 0);
            acc[1][nt] = __builtin_amdgcn_mfma_f32_16x16x32_bf16(
                af1, bq[sb][nt], acc[1][nt], 0, 0, 0);
        }
        // refill freed B slot with B[kc+2] (after MFMAs consumed B[kc])
        if (kc + 2 < 8) {
#pragma unroll
            for (int nt = 0; nt < 8; ++nt)
                bq[sb][nt] = bgl[(kc + 2) * 1024 + nt * 64];
        }
        asm volatile("" ::: "memory");
    }

    // Epilogue: C layout col = l15, local row = quad*4 + r.
    const float Mv = Mptr[0];
    float p[2][4] = {{0.f, 0.f, 0.f, 0.f}, {0.f, 0.f, 0.f, 0.f}};
#pragma unroll
    for (int nt = 0; nt < 8; ++nt) {
        const int n = nw * 128 + nt * 16 + l15;
        const float qn = qq[b * HH + n];
        const float vn = V_w[n];
#pragma unroll
        for (int mt = 0; mt < 2; ++mt)
#pragma unroll
            for (int r = 0; r < 4; ++r)
                p[mt][r] = fmaf(vn, fast_tanh(qn + acc[mt][nt][r]), p[mt][r]);
    }
#pragma unroll
    for (int off = 1; off < 16; off <<= 1)
#pragma unroll
        for (int mt = 0; mt < 2; ++mt)
#pragma unroll
            for (int r = 0; r < 4; ++r)
                p[mt][r] += __shfl_xor(p[mt][r], off);

    if (nw == 0 && l15 == 0) {
#pragma unroll
        for (int mt = 0; mt < 2; ++mt)
            *(float4*)&sc_lds[mw * 32 + mt * 16 + quad * 4] =
                make_float4(p[mt][0], p[mt][1], p[mt][2], p[mt][3]);
    }
    __syncthreads();
    if (nw == 1 && l15 == 0) {
#pragma unroll
        for (int mt = 0; mt < 2; ++mt) {
            const int row = mw * 32 + mt * 16 + quad * 4;
            float4 h = *(const float4*)&sc_lds[row];
            float4 v = make_float4(__expf(h.x + p[mt][0] - Mv),
                                   __expf(h.y + p[mt][1] - Mv),
                                   __expf(h.z + p[mt][2] - Mv),
                                   __expf(h.w + p[mt][3] - Mv));
            *(float4*)&sc_lds[row] = v;
            *(float4*)&wtilde_out[b * SS + s0 + row] = v;
        }
    }
    __syncthreads();

    // Local ctx partial over this tile's 64 rows (cache-hot: just streamed).
    const int tr = t >> 6;
    const int h0 = (t & 63) * 4;
    float4 a = make_float4(0.f, 0.f, 0.f, 0.f);
    const float* ep = enc + ((size_t)(b * SS + s0)) * HH;
#pragma unroll
    for (int jj = 0; jj < 16; ++jj) {
        const int j = jj * 4 + tr;
        const float4 e = *(const float4*)(ep + (size_t)j * HH + h0);
        const float w = sc_lds[j];
        a.x = fmaf(w, e.x, a.x);
        a.y = fmaf(w, e.y, a.y);
        a.z = fmaf(w, e.z, a.z);
        a.w = fmaf(w, e.w, a.w);
    }
    *(float4*)&accl[tr][h0] = a;
    __syncthreads();

    part[((size_t)(b * 64 + c)) * HH + t] =
        accl[0][t] + accl[1][t] + accl[2][t] + accl[3][t];
}

// ---------------------------------------------------------------------------
// Finish: grid (BB), block 256. l = sum_s wtilde (read from d_out),
// weights normalized in place; ctx = (sum_c part)/l.
// ---------------------------------------------------------------------------
__global__ __launch_bounds__(256)
void finish_kernel(const float* __restrict__ part,
                   float* __restrict__ weights_out,
                   float* __restrict__ ctx_out) {
    __shared__ float red[256];
    __shared__ float linv_s;
    const int b = blockIdx.x;
    const int t = threadIdx.x;

    float4* wo4 = (float4*)(weights_out + (size_t)b * SS);
    float4 vals[4];
    float l = 0.f;
#pragma unroll
    for (int i = 0; i < 4; ++i) {
        vals[i] = wo4[i * 256 + t];
        l += vals[i].x + vals[i].y + vals[i].z + vals[i].w;
    }
    red[t] = l;
    __syncthreads();
    for (int off = 128; off > 0; off >>= 1) {
        if (t < off) red[t] += red[t + off];
        __syncthreads();
    }
    if (t == 0) linv_s = 1.f / red[0];
    __syncthreads();
    const float linv = linv_s;

#pragma unroll
    for (int i = 0; i < 4; ++i) {
        const float4 v = vals[i];
        wo4[i * 256 + t] =
            make_float4(v.x * linv, v.y * linv, v.z * linv, v.w * linv);
    }

    float a = 0.f;
#pragma unroll 8
    for (int c = 0; c < 64; ++c)
        a += part[((size_t)(b * 64 + c)) * HH + t];
    ctx_out[b * HH + t] = a * linv;
}

// ---------------------------------------------------------------------------
extern "C" void kernel_launch(void* const* d_in, const int* in_sizes, int n_in,
                              void* d_out, int out_size, void* d_ws, size_t ws_size,
                              hipStream_t stream) {
    const float* hidden = (const float*)d_in[0];
    const float* enc    = (const float*)d_in[1];
    const float* W1_w   = (const float*)d_in[2];
    const float* W1_b   = (const float*)d_in[3];
    const float* W2_w   = (const float*)d_in[4];
    const float* W2_b   = (const float*)d_in[5];
    const float* V_w    = (const float*)d_in[6];
    const float* V_b    = (const float*)d_in[7];
    (void)V_b;  // cancels in the shifted softmax

    float* out_weights = (float*)d_out;                 // B*S
    float* out_ctx     = (float*)d_out + BB * SS;       // B*H

    float* ws      = (float*)d_ws;
    float* ws_qq   = ws;                                 // 8192
    float* ws_part = ws_qq + BB * HH;                    // 524288
    float* ws_M    = ws_part + BB * 64 * HH;             // 1
    ushort* ws_w2  = (ushort*)(ws_M + 4);                // 65536 bf16

    prep_kernel<<<dim3(256 + BB + 1), dim3(256), 0, stream>>>(
        W2_w, ws_w2, hidden, W1_w, W1_b, W2_b, V_w, ws_qq, ws_M);
    score_ctx_kernel<<<dim3(64, BB), dim3(256), 0, stream>>>(
        enc, ws_w2, ws_qq, V_w, ws_M, out_weights, ws_part);
    finish_kernel<<<dim3(BB), dim3(256), 0, stream>>>(
        ws_part, out_weights, out_ctx);
}